// Round 3
// baseline (205.158 us; speedup 1.0000x reference)
//
#include <hip/hip_runtime.h>
#include <hip/hip_cooperative_groups.h>
#include <math.h>

namespace cg = cooperative_groups;

// Problem constants (fixed by the reference).
#define BB 4
#define SS 2048
#define DD 16
#define HH 16
#define BHS (BB * HH * SS)  // 131072 elements per Q/K/V plane

#if defined(__has_builtin)
#if __has_builtin(__builtin_amdgcn_exp2f)
#define EXP2(x) __builtin_amdgcn_exp2f(x)
#else
#define EXP2(x) exp2f(x)
#endif
#else
#define EXP2(x) exp2f(x)
#endif

#define LOG2E 1.44269504088896340736f

// Predicated accumulate for the diagonal (tail) block: j = J4*4 + jj,
// active iff jj <= lane.
#define TAIL_STEP(k4, v4, jjbase)                                        \
  {                                                                      \
    float e;                                                             \
    e = EXP2(qs * (k4).x); e = ((jjbase) + 0 <= lane) ? e : 0.f;         \
    l0 += e; a0 = fmaf(e, (v4).x, a0);                                   \
    e = EXP2(qs * (k4).y); e = ((jjbase) + 1 <= lane) ? e : 0.f;         \
    l1 += e; a1 = fmaf(e, (v4).y, a1);                                   \
    e = EXP2(qs * (k4).z); e = ((jjbase) + 2 <= lane) ? e : 0.f;         \
    l2 += e; a2 = fmaf(e, (v4).z, a2);                                   \
    e = EXP2(qs * (k4).w); e = ((jjbase) + 3 <= lane) ? e : 0.f;         \
    l3 += e; a3 = fmaf(e, (v4).w, a3);                                   \
  }

#define MAIN_STEP(k4, v4)                                                \
  {                                                                      \
    float e;                                                             \
    e = EXP2(qs * (k4).x); l0 += e; a0 = fmaf(e, (v4).x, a0);            \
    e = EXP2(qs * (k4).y); l1 += e; a1 = fmaf(e, (v4).y, a1);            \
    e = EXP2(qs * (k4).z); l2 += e; a2 = fmaf(e, (v4).z, a2);            \
    e = EXP2(qs * (k4).w); l3 += e; a3 = fmaf(e, (v4).w, a3);            \
  }

// ---------------------------------------------------------------------------
// Single cooperative kernel: phase A (QKV proj) -> grid.sync ->
// phase B (scalar-head causal attention) -> grid.sync -> phase C (out proj).
// All phases use grid 512 x 256. 16.6 KB LDS, reused across phases.
// __launch_bounds__(256, 2): 2 blocks/CU guaranteed -> 512 blocks co-resident.
// ---------------------------------------------------------------------------
__global__ __launch_bounds__(256, 2) void fused_mha_kernel(
    const float* __restrict__ x, const float* __restrict__ w_qkv,
    const float* __restrict__ b_qkv, const float* __restrict__ w_out,
    const float* __restrict__ b_out, float* __restrict__ out,
    float* __restrict__ Q, float* __restrict__ K, float* __restrict__ V,
    float* __restrict__ AO) {
  __shared__ float smem[4160];
  const int t = threadIdx.x;
  const int blk = blockIdx.x;
  cg::grid_group grid = cg::this_grid();

  // ===== Phase A: qkv = x @ w_qkv + b_qkv -> Q/K/V[b][h][s] =====
  {
    float* wt = smem;         // [16h][17 float4]: (wq,wk,wv,pad) per (h,i)
    float* xl = smem + 1088;  // 16 rows x 16, stride 20
    float* bs = smem + 1408;  // 48
    for (int idx = t; idx < DD * 3 * DD; idx += 256) {
      const int i = idx / 48, o = idx % 48;
      wt[(o & 15) * 68 + i * 4 + (o >> 4)] = w_qkv[idx];
    }
    if (t < 3 * DD) bs[t] = b_qkv[t];
    xl[(t >> 4) * 20 + (t & 15)] = x[blk * 256 + t];  // coalesced
    __syncthreads();

    const int row_l = t >> 4, h = t & 15;
    const int row = blk * 16 + row_l;  // b*S + s
    const int b = row >> 11, s = row & (SS - 1);
    const float4* xl4 = (const float4*)xl;
    const float4* wt4 = (const float4*)wt;

    float q = bs[h], k = bs[DD + h], v = bs[2 * DD + h];
#pragma unroll
    for (int g = 0; g < 4; ++g) {
      const float4 xv = xl4[row_l * 5 + g];
      const float xs[4] = {xv.x, xv.y, xv.z, xv.w};
#pragma unroll
      for (int u = 0; u < 4; ++u) {
        const float4 wv = wt4[h * 17 + 4 * g + u];
        q = fmaf(xs[u], wv.x, q);
        k = fmaf(xs[u], wv.y, k);
        v = fmaf(xs[u], wv.z, v);
      }
    }
    const int o = (b * HH + h) * SS + s;
    Q[o] = q; K[o] = k; V[o] = v;
  }

  grid.sync();

  // ===== Phase B: out[b,h,i] = sum_{j<=i} e^{q_i k_j} v_j / sum e^{q_i k_j}
  {
    float* Kl = smem;         // 2048
    float* Vl = smem + 2048;  // 2048
    const int c = blk & 7;
    const int bh = blk >> 3;
    const int b = bh >> 4, h = bh & 15;

    const float4* Kg = (const float4*)(K + (size_t)bh * SS);
    const float4* Vg = (const float4*)(V + (size_t)bh * SS);
    float4* Kl4w = (float4*)Kl;
    float4* Vl4w = (float4*)Vl;
    for (int idx = t; idx < SS / 4; idx += 256) {
      Kl4w[idx] = Kg[idx];
      Vl4w[idx] = Vg[idx];
    }
    __syncthreads();

    const int wv_ = t >> 6, lane = t & 63;
    const int par = (blk >> 8) & 1;  // blocks b, b+256 share a CU: flip map
    const int ww = par ? (3 - wv_) : wv_;
    const int span = (ww == 0) ? c : (ww == 1) ? (15 - c)
                                   : (ww == 2) ? (16 + c) : (31 - c);
    const int i = span * 64 + lane;

    const float qs = Q[bh * SS + i] * LOG2E;  // exp(q k) = exp2(qs k)

    const float4* Kl4 = (const float4*)Kl;
    const float4* Vl4 = (const float4*)Vl;

    float l0 = 0.f, l1 = 0.f, l2 = 0.f, l3 = 0.f;
    float a0 = 0.f, a1 = 0.f, a2 = 0.f, a3 = 0.f;

    const int J4 = span * 16;  // float4-groups before the diagonal block

    // Register-rotation prefetch: K0..K3/V0..V3 hold groups [p, p+4);
    // next iteration's groups are loaded before computing on the current.
    float4 K0 = Kl4[0], K1 = Kl4[1], K2 = Kl4[2], K3 = Kl4[3];
    float4 V0 = Vl4[0], V1 = Vl4[1], V2 = Vl4[2], V3 = Vl4[3];
    for (int p = 0; p < J4; p += 4) {
      const float4 nK0 = Kl4[p + 4], nK1 = Kl4[p + 5];
      const float4 nK2 = Kl4[p + 6], nK3 = Kl4[p + 7];
      const float4 nV0 = Vl4[p + 4], nV1 = Vl4[p + 5];
      const float4 nV2 = Vl4[p + 6], nV3 = Vl4[p + 7];
      MAIN_STEP(K0, V0); MAIN_STEP(K1, V1);
      MAIN_STEP(K2, V2); MAIN_STEP(K3, V3);
      K0 = nK0; K1 = nK1; K2 = nK2; K3 = nK3;
      V0 = nV0; V1 = nV1; V2 = nV2; V3 = nV3;
    }

    // Diagonal 64-j block: groups J4..J4+3 are already in registers.
    TAIL_STEP(K0, V0, 0); TAIL_STEP(K1, V1, 4);
    TAIL_STEP(K2, V2, 8); TAIL_STEP(K3, V3, 12);
#pragma unroll
    for (int g = 4; g < 16; ++g) {
      const float4 k4 = Kl4[J4 + g];
      const float4 v4 = Vl4[J4 + g];
      TAIL_STEP(k4, v4, 4 * g);
    }

    const float l = (l0 + l1) + (l2 + l3);
    const float a = (a0 + a1) + (a2 + a3);
    AO[((size_t)b * SS + i) * HH + h] = a / l;  // AO[b][s][h]
  }

  grid.sync();

  // ===== Phase C: out = AO @ w_out + b_out =====
  {
    float* wct = smem;         // column d at wct[d*68 + i]
    float* xl = smem + 1088;   // 16 rows x 16, stride 20
    float* bs = smem + 1408;   // 16
    wct[(t & 15) * 68 + (t >> 4)] = w_out[t];  // 256 elements
    if (t < DD) bs[t] = b_out[t];
    xl[(t >> 4) * 20 + (t & 15)] = AO[blk * 256 + t];
    __syncthreads();

    const int row_l = t >> 4, d = t & 15;
    const float4* xl4 = (const float4*)xl;
    const float4* wc4 = (const float4*)wct;

    float y = bs[d];
#pragma unroll
    for (int g = 0; g < 4; ++g) {
      const float4 xv = xl4[row_l * 5 + g];
      const float4 wv = wc4[d * 17 + g];
      y = fmaf(xv.x, wv.x, y);
      y = fmaf(xv.y, wv.y, y);
      y = fmaf(xv.z, wv.z, y);
      y = fmaf(xv.w, wv.w, y);
    }
    out[blk * 256 + t] = y;  // coalesced
  }
}

// ---------------------------------------------------------------------------
extern "C" void kernel_launch(void* const* d_in, const int* in_sizes, int n_in,
                              void* d_out, int out_size, void* d_ws,
                              size_t ws_size, hipStream_t stream) {
  const float* x = (const float*)d_in[0];       // [B,S,D]
  const float* w_qkv = (const float*)d_in[1];   // [D, 3D]
  const float* b_qkv = (const float*)d_in[2];   // [3D]
  const float* w_out = (const float*)d_in[3];   // [D, D]
  const float* b_out = (const float*)d_in[4];   // [D]
  float* out = (float*)d_out;                   // [B,S,D] fp32

  float* ws = (float*)d_ws;
  float* Q = ws;             // [B][H][S]
  float* K = ws + BHS;       // [B][H][S]
  float* V = ws + 2 * BHS;   // [B][H][S]
  float* AO = ws + 3 * BHS;  // [B][S][H]

  void* args[] = {(void*)&x, (void*)&w_qkv, (void*)&b_qkv, (void*)&w_out,
                  (void*)&b_out, (void*)&out, (void*)&Q, (void*)&K,
                  (void*)&V, (void*)&AO};
  hipLaunchCooperativeKernel((const void*)fused_mha_kernel, dim3(512),
                             dim3(256), args, 0, stream);
}

// Round 4
// 102.672 us; speedup vs baseline: 1.9982x; 1.9982x over previous
//
#include <hip/hip_runtime.h>
#include <math.h>

// Problem constants (fixed by the reference).
#define BB 4
#define SS 2048
#define DD 16
#define HH 16
#define BHS (BB * HH * SS)  // 131072 elements per Q/K/V plane

#if defined(__has_builtin)
#if __has_builtin(__builtin_amdgcn_exp2f)
#define EXP2(x) __builtin_amdgcn_exp2f(x)
#else
#define EXP2(x) exp2f(x)
#endif
#else
#define EXP2(x) exp2f(x)
#endif

#define LOG2E 1.44269504088896340736f

// ---------------------------------------------------------------------------
// Kernel A: qkv = x @ w_qkv + b_qkv -> Q/K/V[b][h][s] (transposed).
// 512 blocks x 256 threads; block = 16 rows x 16 h.
// ---------------------------------------------------------------------------
__global__ __launch_bounds__(256) void qkv_kernel(
    const float* __restrict__ x, const float* __restrict__ w,
    const float* __restrict__ bias, float* __restrict__ Q,
    float* __restrict__ K, float* __restrict__ V) {
  __shared__ float wt[HH * 68];  // wt4[h*17 + i] = {wq, wk, wv, pad}
  __shared__ float xl[16 * 20];  // 16 rows x 16 cols, stride 20
  __shared__ float bs[3 * DD];
  const int t = threadIdx.x;

  for (int idx = t; idx < DD * 3 * DD; idx += 256) {
    const int i = idx / 48, o = idx % 48;
    wt[(o & 15) * 68 + i * 4 + (o >> 4)] = w[idx];
  }
  if (t < 3 * DD) bs[t] = bias[t];
  xl[(t >> 4) * 20 + (t & 15)] = x[(size_t)blockIdx.x * 256 + t];
  __syncthreads();

  const int row_l = t >> 4, h = t & 15;
  const int row = blockIdx.x * 16 + row_l;  // b*S + s
  const int b = row >> 11, s = row & (SS - 1);
  const float4* xl4 = (const float4*)xl;
  const float4* wt4 = (const float4*)wt;

  float q = bs[h], k = bs[DD + h], v = bs[2 * DD + h];
#pragma unroll
  for (int g = 0; g < 4; ++g) {
    const float4 xv = xl4[row_l * 5 + g];
    const float xs[4] = {xv.x, xv.y, xv.z, xv.w};
#pragma unroll
    for (int u = 0; u < 4; ++u) {
      const float4 wv = wt4[h * 17 + 4 * g + u];
      q = fmaf(xs[u], wv.x, q);
      k = fmaf(xs[u], wv.y, k);
      v = fmaf(xs[u], wv.z, v);
    }
  }
  const int o = (b * HH + h) * SS + s;
  Q[o] = q; K[o] = k; V[o] = v;
}

// ---------------------------------------------------------------------------
// Kernel B: scalar-head causal attention, R=4 queries/lane, j split by
// 64-block parity. Grid: 64 bh x 2 qp x 2 jp = 256 blocks x 256 thr.
// Wave w, replica r owns query-block qb = qp + 2w + 8r (i = qb*64 + lane).
// Block covers j-blocks jb = jp + 2*idx. Full if jb < qb, diagonal iff
// qp==jp at idx == F0+4r (predicated by lane). Partial (a,l) -> P[jp][bh][i].
// ---------------------------------------------------------------------------
#define ACC4(QS, LL, AA, K4, V4)                                   \
  {                                                                \
    float e;                                                       \
    e = EXP2((QS) * (K4).x); LL += e; AA = fmaf(e, (V4).x, AA);    \
    e = EXP2((QS) * (K4).y); LL += e; AA = fmaf(e, (V4).y, AA);    \
    e = EXP2((QS) * (K4).z); LL += e; AA = fmaf(e, (V4).z, AA);    \
    e = EXP2((QS) * (K4).w); LL += e; AA = fmaf(e, (V4).w, AA);    \
  }

#define ACC4P(QS, LL, AA, K4, V4, JJ)                              \
  {                                                                \
    float e;                                                       \
    e = EXP2((QS) * (K4).x); e = ((JJ) + 0 <= lane) ? e : 0.f;     \
    LL += e; AA = fmaf(e, (V4).x, AA);                             \
    e = EXP2((QS) * (K4).y); e = ((JJ) + 1 <= lane) ? e : 0.f;     \
    LL += e; AA = fmaf(e, (V4).y, AA);                             \
    e = EXP2((QS) * (K4).z); e = ((JJ) + 2 <= lane) ? e : 0.f;     \
    LL += e; AA = fmaf(e, (V4).z, AA);                             \
    e = EXP2((QS) * (K4).w); e = ((JJ) + 3 <= lane) ? e : 0.f;     \
    LL += e; AA = fmaf(e, (V4).w, AA);                             \
  }

__global__ __launch_bounds__(256, 1) void attn_kernel(
    const float* __restrict__ Q, const float* __restrict__ K,
    const float* __restrict__ V, float2* __restrict__ P) {
  __shared__ float Kl[1024];  // this block's 16 parity-jb blocks of K
  __shared__ float Vl[1024];
  const int blk = blockIdx.x;
  const int jp = blk & 1;
  const int qp = (blk >> 1) & 1;
  const int bh = blk >> 2;  // 0..63
  const int t = threadIdx.x;
  const int w = t >> 6, lane = t & 63;

  // Stage the 16 parity-selected 64-j blocks (float4-coalesced, 1 per thread).
  {
    const float4* Kg4 = (const float4*)(K + (size_t)bh * SS);
    const float4* Vg4 = (const float4*)(V + (size_t)bh * SS);
    float4* Kl4w = (float4*)Kl;
    float4* Vl4w = (float4*)Vl;
    const int idx = t >> 4, u = t & 15;
    const int src = (jp + 2 * idx) * 16 + u;
    Kl4w[t] = Kg4[src];
    Vl4w[t] = Vg4[src];
  }
  __syncthreads();

  // Replica query blocks: qb_r = qp + 2w + 8r.
  const int qb0 = qp + 2 * w;
  const float qs0 = Q[bh * SS + (qb0 + 0) * 64 + lane] * LOG2E;
  const float qs1 = Q[bh * SS + (qb0 + 8) * 64 + lane] * LOG2E;
  const float qs2 = Q[bh * SS + (qb0 + 16) * 64 + lane] * LOG2E;
  const float qs3 = Q[bh * SS + (qb0 + 24) * 64 + lane] * LOG2E;

  float l0 = 0.f, l1 = 0.f, l2 = 0.f, l3 = 0.f;
  float a0 = 0.f, a1 = 0.f, a2 = 0.f, a3 = 0.f;

  const int HD = (qp == jp);               // diagonals exist in this block
  const int F0 = w + ((qp > jp) ? 1 : 0);  // full-block count for r=0
  const int MAXIDX = F0 + 12 + HD;         // loop bound (wave-uniform)

  const float4* Kl4 = (const float4*)Kl;
  const float4* Vl4 = (const float4*)Vl;

  for (int idx = 0; idx < MAXIDX; ++idx) {
    const bool f0 = idx < F0, f1 = idx < F0 + 4, f2 = idx < F0 + 8,
               f3 = idx < F0 + 12;
    const bool d0 = HD && (idx == F0), d1 = HD && (idx == F0 + 4),
               d2 = HD && (idx == F0 + 8), d3 = HD && (idx == F0 + 12);
#pragma unroll
    for (int s = 0; s < 4; ++s) {  // 16 j's per sub-chunk
      const float4 k0 = Kl4[idx * 16 + s * 4 + 0];
      const float4 k1 = Kl4[idx * 16 + s * 4 + 1];
      const float4 k2 = Kl4[idx * 16 + s * 4 + 2];
      const float4 k3 = Kl4[idx * 16 + s * 4 + 3];
      const float4 v0 = Vl4[idx * 16 + s * 4 + 0];
      const float4 v1 = Vl4[idx * 16 + s * 4 + 1];
      const float4 v2 = Vl4[idx * 16 + s * 4 + 2];
      const float4 v3 = Vl4[idx * 16 + s * 4 + 3];
      const int jj = s * 16;
      if (f0) {
        ACC4(qs0, l0, a0, k0, v0); ACC4(qs0, l0, a0, k1, v1);
        ACC4(qs0, l0, a0, k2, v2); ACC4(qs0, l0, a0, k3, v3);
      } else if (d0) {
        ACC4P(qs0, l0, a0, k0, v0, jj + 0); ACC4P(qs0, l0, a0, k1, v1, jj + 4);
        ACC4P(qs0, l0, a0, k2, v2, jj + 8); ACC4P(qs0, l0, a0, k3, v3, jj + 12);
      }
      if (f1) {
        ACC4(qs1, l1, a1, k0, v0); ACC4(qs1, l1, a1, k1, v1);
        ACC4(qs1, l1, a1, k2, v2); ACC4(qs1, l1, a1, k3, v3);
      } else if (d1) {
        ACC4P(qs1, l1, a1, k0, v0, jj + 0); ACC4P(qs1, l1, a1, k1, v1, jj + 4);
        ACC4P(qs1, l1, a1, k2, v2, jj + 8); ACC4P(qs1, l1, a1, k3, v3, jj + 12);
      }
      if (f2) {
        ACC4(qs2, l2, a2, k0, v0); ACC4(qs2, l2, a2, k1, v1);
        ACC4(qs2, l2, a2, k2, v2); ACC4(qs2, l2, a2, k3, v3);
      } else if (d2) {
        ACC4P(qs2, l2, a2, k0, v0, jj + 0); ACC4P(qs2, l2, a2, k1, v1, jj + 4);
        ACC4P(qs2, l2, a2, k2, v2, jj + 8); ACC4P(qs2, l2, a2, k3, v3, jj + 12);
      }
      if (f3) {
        ACC4(qs3, l3, a3, k0, v0); ACC4(qs3, l3, a3, k1, v1);
        ACC4(qs3, l3, a3, k2, v2); ACC4(qs3, l3, a3, k3, v3);
      } else if (d3) {
        ACC4P(qs3, l3, a3, k0, v0, jj + 0); ACC4P(qs3, l3, a3, k1, v1, jj + 4);
        ACC4P(qs3, l3, a3, k2, v2, jj + 8); ACC4P(qs3, l3, a3, k3, v3, jj + 12);
      }
    }
  }

  // Partial (a, l) per query-instance; coalesced float2 stores.
  float2* Pp = P + (size_t)(jp * 64 + bh) * SS;
  Pp[(qb0 + 0) * 64 + lane] = make_float2(a0, l0);
  Pp[(qb0 + 8) * 64 + lane] = make_float2(a1, l1);
  Pp[(qb0 + 16) * 64 + lane] = make_float2(a2, l2);
  Pp[(qb0 + 24) * 64 + lane] = make_float2(a3, l3);
}

// ---------------------------------------------------------------------------
// Kernel C: combine partials -> AO[row][h] in LDS, then out = AO@w_out+b_out.
// 512 blocks x 256 threads; block = 16 rows.
// ---------------------------------------------------------------------------
__global__ __launch_bounds__(256) void proj_kernel(
    const float2* __restrict__ P, const float* __restrict__ w,
    const float* __restrict__ bias, float* __restrict__ out) {
  __shared__ float wct[DD * 68];  // column d at wct[d*68 + i]
  __shared__ float aol[256];      // aol[row_l*16 + h]
  __shared__ float bs[DD];
  const int t = threadIdx.x;
  const int b = blockIdx.x >> 7;             // 16 rows per block, 2048 rows/b
  const int s_base = (blockIdx.x * 16) & (SS - 1);

  wct[(t & 15) * 68 + (t >> 4)] = w[t];
  if (t < DD) bs[t] = bias[t];

  // Combine: thread t -> (h = t>>4, row_l = t&15); consecutive row_l ->
  // consecutive i -> 128B-coalesced float2 loads per h-group.
  {
    const int h = t >> 4, row_l = t & 15;
    const int bh = b * HH + h;
    const float2 p0 = P[(size_t)bh * SS + s_base + row_l];
    const float2 p1 = P[(size_t)(64 + bh) * SS + s_base + row_l];
    aol[row_l * 16 + h] = (p0.x + p1.x) / (p0.y + p1.y);
  }
  __syncthreads();

  const int row_l = t >> 4, d = t & 15;
  const float4* ao4 = (const float4*)aol;
  const float4* wc4 = (const float4*)wct;

  float y = bs[d];
#pragma unroll
  for (int g = 0; g < 4; ++g) {
    const float4 xv = ao4[row_l * 4 + g];
    const float4 wv = wc4[d * 17 + g];
    y = fmaf(xv.x, wv.x, y);
    y = fmaf(xv.y, wv.y, y);
    y = fmaf(xv.z, wv.z, y);
    y = fmaf(xv.w, wv.w, y);
  }
  out[(size_t)blockIdx.x * 256 + t] = y;
}

// ---------------------------------------------------------------------------
extern "C" void kernel_launch(void* const* d_in, const int* in_sizes, int n_in,
                              void* d_out, int out_size, void* d_ws,
                              size_t ws_size, hipStream_t stream) {
  const float* x = (const float*)d_in[0];       // [B,S,D]
  const float* w_qkv = (const float*)d_in[1];   // [D, 3D]
  const float* b_qkv = (const float*)d_in[2];   // [3D]
  const float* w_out = (const float*)d_in[3];   // [D, D]
  const float* b_out = (const float*)d_in[4];   // [D]
  float* out = (float*)d_out;                   // [B,S,D] fp32

  float* ws = (float*)d_ws;
  float* Q = ws;             // [B][H][S]
  float* K = ws + BHS;       // [B][H][S]
  float* V = ws + 2 * BHS;   // [B][H][S]
  float2* P = (float2*)(ws + 3 * BHS);  // [2 jp][64 bh][2048 i] float2(a,l)

  qkv_kernel<<<512, 256, 0, stream>>>(x, w_qkv, b_qkv, Q, K, V);
  attn_kernel<<<256, 256, 0, stream>>>(Q, K, V, P);
  proj_kernel<<<512, 256, 0, stream>>>(P, w_out, b_out, out);
}

// Round 5
// 99.476 us; speedup vs baseline: 2.0624x; 1.0321x over previous
//
#include <hip/hip_runtime.h>
#include <math.h>

// Problem constants (fixed by the reference).
#define BB 4
#define SS 2048
#define DD 16
#define HH 16
#define BHS (BB * HH * SS)  // 131072 elements per Q/K/V plane

#if defined(__has_builtin)
#if __has_builtin(__builtin_amdgcn_exp2f)
#define EXP2(x) __builtin_amdgcn_exp2f(x)
#else
#define EXP2(x) exp2f(x)
#endif
#else
#define EXP2(x) exp2f(x)
#endif

#define LOG2E 1.44269504088896340736f

// ---------------------------------------------------------------------------
// Kernel A: qkv = x @ w_qkv + b_qkv -> Q/K/V[b][h][s] (transposed).
// 512 blocks x 256 threads; block = 16 rows x 16 h.
// ---------------------------------------------------------------------------
__global__ __launch_bounds__(256) void qkv_kernel(
    const float* __restrict__ x, const float* __restrict__ w,
    const float* __restrict__ bias, float* __restrict__ Q,
    float* __restrict__ K, float* __restrict__ V) {
  __shared__ float wt[HH * 68];  // wt4[h*17 + i] = {wq, wk, wv, pad}
  __shared__ float xl[16 * 20];  // 16 rows x 16 cols, stride 20
  __shared__ float bs[3 * DD];
  const int t = threadIdx.x;

  for (int idx = t; idx < DD * 3 * DD; idx += 256) {
    const int i = idx / 48, o = idx % 48;
    wt[(o & 15) * 68 + i * 4 + (o >> 4)] = w[idx];
  }
  if (t < 3 * DD) bs[t] = bias[t];
  xl[(t >> 4) * 20 + (t & 15)] = x[(size_t)blockIdx.x * 256 + t];
  __syncthreads();

  const int row_l = t >> 4, h = t & 15;
  const int row = blockIdx.x * 16 + row_l;  // b*S + s
  const int b = row >> 11, s = row & (SS - 1);
  const float4* xl4 = (const float4*)xl;
  const float4* wt4 = (const float4*)wt;

  float q = bs[h], k = bs[DD + h], v = bs[2 * DD + h];
#pragma unroll
  for (int g = 0; g < 4; ++g) {
    const float4 xv = xl4[row_l * 5 + g];
    const float xs[4] = {xv.x, xv.y, xv.z, xv.w};
#pragma unroll
    for (int u = 0; u < 4; ++u) {
      const float4 wv = wt4[h * 17 + 4 * g + u];
      q = fmaf(xs[u], wv.x, q);
      k = fmaf(xs[u], wv.y, k);
      v = fmaf(xs[u], wv.z, v);
    }
  }
  const int o = (b * HH + h) * SS + s;
  Q[o] = q; K[o] = k; V[o] = v;
}

// ---------------------------------------------------------------------------
// Kernel B: scalar-head causal attention with SCALAR (wave-uniform) K/V.
// K/V values are identical across lanes for a given j, so they are read
// through the scalar pipe (s_load_dwordx16) and consumed as SGPR operands
// of v_mul/v_fmac -- no LDS, no staging, no __syncthreads.
//
// Grid: 64 bh x 8 c x 8 jp = 4096 one-wave blocks (64 thr) -> 16 waves/CU.
// Wave (bh,c,jp) handles queries qb in {c, 15-c, 16+c, 31-c} (64 lanes each,
// i = qb*64 + lane) against j-blocks jb == jp (mod 8), jb < qb, plus the
// predicated diagonal block when qb == jp (mod 8). Partial (a,l) per jp.
// ---------------------------------------------------------------------------
__global__ __launch_bounds__(64, 4) void attn_kernel(
    const float* __restrict__ Q, const float* __restrict__ K,
    const float* __restrict__ V, float2* __restrict__ P) {
  const int blk = blockIdx.x;
  const int jp = blk & 7;
  const int c = (blk >> 3) & 7;
  const int bh = blk >> 6;  // 0..63
  const int lane = threadIdx.x;  // 64-thread block = one wave

  const float* __restrict__ Kb = K + (size_t)bh * SS;
  const float* __restrict__ Vb = V + (size_t)bh * SS;
  const float* __restrict__ Qb = Q + (size_t)bh * SS;

  const int qbs[4] = {c, 15 - c, 16 + c, 31 - c};
  float qsv[4], lo[4], ao[4];
#pragma unroll
  for (int r = 0; r < 4; ++r) qsv[r] = Qb[qbs[r] * 64 + lane] * LOG2E;

#pragma unroll
  for (int r = 0; r < 4; ++r) {
    const int qb = qbs[r];
    const float qs = qsv[r];
    float la = 0.f, lb = 0.f, aa = 0.f, ab = 0.f;

    // Full j-blocks of this parity class: jb = jp + 8*s, s in [0, nfull).
    const int nfull = (qb > jp) ? ((qb - jp + 7) >> 3) : 0;
    for (int s = 0; s < nfull; ++s) {
      const float* kp = Kb + ((jp + 8 * s) << 6);  // wave-uniform -> s_load
      const float* vp = Vb + ((jp + 8 * s) << 6);
#pragma unroll
      for (int u = 0; u < 64; u += 2) {
        const float e0 = EXP2(qs * kp[u]);
        la += e0; aa = fmaf(e0, vp[u], aa);
        const float e1 = EXP2(qs * kp[u + 1]);
        lb += e1; ab = fmaf(e1, vp[u + 1], ab);
      }
    }

    // Diagonal block (j-block == query-block): active iff u <= lane.
    if ((qb & 7) == jp) {
      const float* kp = Kb + (qb << 6);
      const float* vp = Vb + (qb << 6);
#pragma unroll
      for (int u = 0; u < 64; u += 2) {
        float e0 = EXP2(qs * kp[u]);
        e0 = (u <= lane) ? e0 : 0.f;
        la += e0; aa = fmaf(e0, vp[u], aa);
        float e1 = EXP2(qs * kp[u + 1]);
        e1 = (u + 1 <= lane) ? e1 : 0.f;
        lb += e1; ab = fmaf(e1, vp[u + 1], ab);
      }
    }
    lo[r] = la + lb;
    ao[r] = aa + ab;
  }

  // Partial (a, l) per query-instance; coalesced float2 stores.
  float2* Pp = P + (size_t)(jp * 64 + bh) * SS;
#pragma unroll
  for (int r = 0; r < 4; ++r) {
    Pp[qbs[r] * 64 + lane] = make_float2(ao[r], lo[r]);
  }
}

// ---------------------------------------------------------------------------
// Kernel C: combine 8 partials -> AO[row][h] in LDS, then out = AO@w+b.
// 512 blocks x 256 threads; block = 16 rows.
// ---------------------------------------------------------------------------
__global__ __launch_bounds__(256) void proj_kernel(
    const float2* __restrict__ P, const float* __restrict__ w,
    const float* __restrict__ bias, float* __restrict__ out) {
  __shared__ float wct[DD * 68];  // column d at wct[d*68 + i]
  __shared__ float aol[256];      // aol[row_l*16 + h]
  __shared__ float bs[DD];
  const int t = threadIdx.x;
  const int b = blockIdx.x >> 7;  // 128 blocks per batch
  const int s_base = (blockIdx.x * 16) & (SS - 1);

  wct[(t & 15) * 68 + (t >> 4)] = w[t];
  if (t < DD) bs[t] = bias[t];

  // Combine: thread t -> (h = t>>4, row_l = t&15); consecutive row_l gives
  // 128B-contiguous float2 loads per (h, jp) group.
  {
    const int h = t >> 4, row_l = t & 15;
    const int bh = b * HH + h;
    float ax = 0.f, lx = 0.f;
#pragma unroll
    for (int jp = 0; jp < 8; ++jp) {
      const float2 p = P[(size_t)(jp * 64 + bh) * SS + s_base + row_l];
      ax += p.x; lx += p.y;
    }
    aol[row_l * 16 + h] = ax / lx;
  }
  __syncthreads();

  const int row_l = t >> 4, d = t & 15;
  const float4* ao4 = (const float4*)aol;
  const float4* wc4 = (const float4*)wct;

  float y = bs[d];
#pragma unroll
  for (int g = 0; g < 4; ++g) {
    const float4 xv = ao4[row_l * 4 + g];
    const float4 wv = wc4[d * 17 + g];
    y = fmaf(xv.x, wv.x, y);
    y = fmaf(xv.y, wv.y, y);
    y = fmaf(xv.z, wv.z, y);
    y = fmaf(xv.w, wv.w, y);
  }
  out[(size_t)blockIdx.x * 256 + t] = y;
}

// ---------------------------------------------------------------------------
extern "C" void kernel_launch(void* const* d_in, const int* in_sizes, int n_in,
                              void* d_out, int out_size, void* d_ws,
                              size_t ws_size, hipStream_t stream) {
  const float* x = (const float*)d_in[0];       // [B,S,D]
  const float* w_qkv = (const float*)d_in[1];   // [D, 3D]
  const float* b_qkv = (const float*)d_in[2];   // [3D]
  const float* w_out = (const float*)d_in[3];   // [D, D]
  const float* b_out = (const float*)d_in[4];   // [D]
  float* out = (float*)d_out;                   // [B,S,D] fp32

  float* ws = (float*)d_ws;
  float* Q = ws;             // [B][H][S]
  float* K = ws + BHS;       // [B][H][S]
  float* V = ws + 2 * BHS;   // [B][H][S]
  float2* P = (float2*)(ws + 3 * BHS);  // [8 jp][64 bh][2048 i] float2(a,l)

  qkv_kernel<<<512, 256, 0, stream>>>(x, w_qkv, b_qkv, Q, K, V);
  attn_kernel<<<4096, 64, 0, stream>>>(Q, K, V, P);
  proj_kernel<<<512, 256, 0, stream>>>(P, w_out, b_out, out);
}

// Round 6
// 95.845 us; speedup vs baseline: 2.1405x; 1.0379x over previous
//
#include <hip/hip_runtime.h>
#include <math.h>

// Problem constants (fixed by the reference).
#define BB 4
#define SS 2048
#define DD 16
#define HH 16
#define BHS (BB * HH * SS)  // 131072 elements per Q/K/V plane

#if defined(__has_builtin)
#if __has_builtin(__builtin_amdgcn_exp2f)
#define EXP2(x) __builtin_amdgcn_exp2f(x)
#else
#define EXP2(x) exp2f(x)
#endif
#else
#define EXP2(x) exp2f(x)
#endif

#define LOG2E 1.44269504088896340736f

// ---------------------------------------------------------------------------
// Kernel A: qkv = x @ w_qkv + b_qkv -> Q/K/V[b][h][s] (transposed).
// 512 blocks x 256 threads; block = 16 rows x 16 h.
// ---------------------------------------------------------------------------
__global__ __launch_bounds__(256) void qkv_kernel(
    const float* __restrict__ x, const float* __restrict__ w,
    const float* __restrict__ bias, float* __restrict__ Q,
    float* __restrict__ K, float* __restrict__ V) {
  __shared__ float wt[HH * 68];  // wt4[h*17 + i] = {wq, wk, wv, pad}
  __shared__ float xl[16 * 20];  // 16 rows x 16 cols, stride 20
  __shared__ float bs[3 * DD];
  const int t = threadIdx.x;

  for (int idx = t; idx < DD * 3 * DD; idx += 256) {
    const int i = idx / 48, o = idx % 48;
    wt[(o & 15) * 68 + i * 4 + (o >> 4)] = w[idx];
  }
  if (t < 3 * DD) bs[t] = bias[t];
  xl[(t >> 4) * 20 + (t & 15)] = x[(size_t)blockIdx.x * 256 + t];
  __syncthreads();

  const int row_l = t >> 4, h = t & 15;
  const int row = blockIdx.x * 16 + row_l;  // b*S + s
  const int b = row >> 11, s = row & (SS - 1);
  const float4* xl4 = (const float4*)xl;
  const float4* wt4 = (const float4*)wt;

  float q = bs[h], k = bs[DD + h], v = bs[2 * DD + h];
#pragma unroll
  for (int g = 0; g < 4; ++g) {
    const float4 xv = xl4[row_l * 5 + g];
    const float xs[4] = {xv.x, xv.y, xv.z, xv.w};
#pragma unroll
    for (int u = 0; u < 4; ++u) {
      const float4 wv = wt4[h * 17 + 4 * g + u];
      q = fmaf(xs[u], wv.x, q);
      k = fmaf(xs[u], wv.y, k);
      v = fmaf(xs[u], wv.z, v);
    }
  }
  const int o = (b * HH + h) * SS + s;
  Q[o] = q; K[o] = k; V[o] = v;
}

// ---------------------------------------------------------------------------
// Kernel B: scalar-head causal attention. R4 structure (LDS broadcast reads,
// K/V chunks shared in registers across 4 replicas, wave-uniform slot bounds,
// predicated diagonal) with j split mod-8 for 4x occupancy:
// grid = 64 bh x 2 qp x 8 jp = 1024 blocks x 256 thr -> 4 blocks/CU,
// 4 waves/SIMD. LDS = 2 KB/block.
// Wave w, replica r: qb = qp + 2*perm + 8r, perm = (r&1) ? 3-w : w
// (sum of qb per wave is constant -> balanced waves).
// Slots m = 0..3 hold j-blocks jb = jp + 8m. Replica r: full iff m < fr,
// fr = r + (d>0), d = qp+2*perm-jp; diagonal at m == r iff d == 0.
// Partial (a,l) -> P[jp][bh][i]; kernel C combines the 8 partials.
// ---------------------------------------------------------------------------
#define ACC4(QS, LL, AA, K4, V4)                                   \
  {                                                                \
    float e;                                                       \
    e = EXP2((QS) * (K4).x); LL += e; AA = fmaf(e, (V4).x, AA);    \
    e = EXP2((QS) * (K4).y); LL += e; AA = fmaf(e, (V4).y, AA);    \
    e = EXP2((QS) * (K4).z); LL += e; AA = fmaf(e, (V4).z, AA);    \
    e = EXP2((QS) * (K4).w); LL += e; AA = fmaf(e, (V4).w, AA);    \
  }

#define ACC4P(QS, LL, AA, K4, V4, JJ)                              \
  {                                                                \
    float e;                                                       \
    e = EXP2((QS) * (K4).x); e = ((JJ) + 0 <= lane) ? e : 0.f;     \
    LL += e; AA = fmaf(e, (V4).x, AA);                             \
    e = EXP2((QS) * (K4).y); e = ((JJ) + 1 <= lane) ? e : 0.f;     \
    LL += e; AA = fmaf(e, (V4).y, AA);                             \
    e = EXP2((QS) * (K4).z); e = ((JJ) + 2 <= lane) ? e : 0.f;     \
    LL += e; AA = fmaf(e, (V4).z, AA);                             \
    e = EXP2((QS) * (K4).w); e = ((JJ) + 3 <= lane) ? e : 0.f;     \
    LL += e; AA = fmaf(e, (V4).w, AA);                             \
  }

__global__ __launch_bounds__(256, 4) void attn_kernel(
    const float* __restrict__ Q, const float* __restrict__ K,
    const float* __restrict__ V, float2* __restrict__ P) {
  __shared__ float Kl[256];  // 4 j-blocks (jb = jp + 8m) of 64 floats
  __shared__ float Vl[256];
  const int blk = blockIdx.x;
  const int jp = blk & 7;
  const int qp = (blk >> 3) & 1;
  const int bh = blk >> 4;  // 0..63
  const int t = threadIdx.x;
  const int w = t >> 6, lane = t & 63;

  // Stage the 4 parity-selected 64-j blocks (threads 0..63: K, 64..127: V).
  {
    const float4* Kg4 = (const float4*)(K + (size_t)bh * SS);
    const float4* Vg4 = (const float4*)(V + (size_t)bh * SS);
    if (t < 64) {
      const int m = t >> 4, u = t & 15;
      ((float4*)Kl)[t] = Kg4[(jp + 8 * m) * 16 + u];
    } else if (t < 128) {
      const int tt = t - 64;
      const int m = tt >> 4, u = tt & 15;
      ((float4*)Vl)[tt] = Vg4[(jp + 8 * m) * 16 + u];
    }
  }
  __syncthreads();

  // Replicas: qb_r = qp + 2*perm_r + 8r, perm_r = (r&1) ? 3-w : w.
  int qbr[4], fr[4], dr[4];
  float qsv[4];
  const float* Qb = Q + (size_t)bh * SS;
#pragma unroll
  for (int r = 0; r < 4; ++r) {
    const int perm = (r & 1) ? (3 - w) : w;
    const int d = qp + 2 * perm - jp;
    qbr[r] = qp + 2 * perm + 8 * r;
    fr[r] = r + ((d > 0) ? 1 : 0);
    dr[r] = (d == 0);
    qsv[r] = Qb[qbr[r] * 64 + lane] * LOG2E;
  }
  const int d3 = qp + 2 * (3 - w) - jp;         // r=3 is odd -> perm = 3-w
  const int MAXIDX = 3 + ((d3 >= 0) ? 1 : 0);   // wave-uniform

  float l0 = 0.f, l1 = 0.f, l2 = 0.f, l3 = 0.f;
  float a0 = 0.f, a1 = 0.f, a2 = 0.f, a3 = 0.f;

  const float4* Kl4 = (const float4*)Kl;
  const float4* Vl4 = (const float4*)Vl;

  for (int m = 0; m < MAXIDX; ++m) {
    const bool f0 = m < fr[0], f1 = m < fr[1], f2 = m < fr[2], f3 = m < fr[3];
    const bool g0 = dr[0] && (m == 0), g1 = dr[1] && (m == 1),
               g2 = dr[2] && (m == 2), g3 = dr[3] && (m == 3);
#pragma unroll
    for (int s = 0; s < 4; ++s) {  // 16 j's per chunk, shared across replicas
      const float4 k0 = Kl4[m * 16 + s * 4 + 0];
      const float4 k1 = Kl4[m * 16 + s * 4 + 1];
      const float4 k2 = Kl4[m * 16 + s * 4 + 2];
      const float4 k3 = Kl4[m * 16 + s * 4 + 3];
      const float4 v0 = Vl4[m * 16 + s * 4 + 0];
      const float4 v1 = Vl4[m * 16 + s * 4 + 1];
      const float4 v2 = Vl4[m * 16 + s * 4 + 2];
      const float4 v3 = Vl4[m * 16 + s * 4 + 3];
      const int jj = s * 16;
      if (f0) {
        ACC4(qsv[0], l0, a0, k0, v0); ACC4(qsv[0], l0, a0, k1, v1);
        ACC4(qsv[0], l0, a0, k2, v2); ACC4(qsv[0], l0, a0, k3, v3);
      } else if (g0) {
        ACC4P(qsv[0], l0, a0, k0, v0, jj + 0); ACC4P(qsv[0], l0, a0, k1, v1, jj + 4);
        ACC4P(qsv[0], l0, a0, k2, v2, jj + 8); ACC4P(qsv[0], l0, a0, k3, v3, jj + 12);
      }
      if (f1) {
        ACC4(qsv[1], l1, a1, k0, v0); ACC4(qsv[1], l1, a1, k1, v1);
        ACC4(qsv[1], l1, a1, k2, v2); ACC4(qsv[1], l1, a1, k3, v3);
      } else if (g1) {
        ACC4P(qsv[1], l1, a1, k0, v0, jj + 0); ACC4P(qsv[1], l1, a1, k1, v1, jj + 4);
        ACC4P(qsv[1], l1, a1, k2, v2, jj + 8); ACC4P(qsv[1], l1, a1, k3, v3, jj + 12);
      }
      if (f2) {
        ACC4(qsv[2], l2, a2, k0, v0); ACC4(qsv[2], l2, a2, k1, v1);
        ACC4(qsv[2], l2, a2, k2, v2); ACC4(qsv[2], l2, a2, k3, v3);
      } else if (g2) {
        ACC4P(qsv[2], l2, a2, k0, v0, jj + 0); ACC4P(qsv[2], l2, a2, k1, v1, jj + 4);
        ACC4P(qsv[2], l2, a2, k2, v2, jj + 8); ACC4P(qsv[2], l2, a2, k3, v3, jj + 12);
      }
      if (f3) {
        ACC4(qsv[3], l3, a3, k0, v0); ACC4(qsv[3], l3, a3, k1, v1);
        ACC4(qsv[3], l3, a3, k2, v2); ACC4(qsv[3], l3, a3, k3, v3);
      } else if (g3) {
        ACC4P(qsv[3], l3, a3, k0, v0, jj + 0); ACC4P(qsv[3], l3, a3, k1, v1, jj + 4);
        ACC4P(qsv[3], l3, a3, k2, v2, jj + 8); ACC4P(qsv[3], l3, a3, k3, v3, jj + 12);
      }
    }
  }

  // Partial (a, l) per query-instance; coalesced float2 stores.
  float2* Pp = P + (size_t)(jp * 64 + bh) * SS;
  Pp[qbr[0] * 64 + lane] = make_float2(a0, l0);
  Pp[qbr[1] * 64 + lane] = make_float2(a1, l1);
  Pp[qbr[2] * 64 + lane] = make_float2(a2, l2);
  Pp[qbr[3] * 64 + lane] = make_float2(a3, l3);
}

// ---------------------------------------------------------------------------
// Kernel C: combine 8 partials -> AO[row][h] in LDS, then out = AO@w+b.
// 512 blocks x 256 threads; block = 16 rows.
// ---------------------------------------------------------------------------
__global__ __launch_bounds__(256) void proj_kernel(
    const float2* __restrict__ P, const float* __restrict__ w,
    const float* __restrict__ bias, float* __restrict__ out) {
  __shared__ float wct[DD * 68];  // column d at wct[d*68 + i]
  __shared__ float aol[256];      // aol[row_l*16 + h]
  __shared__ float bs[DD];
  const int t = threadIdx.x;
  const int b = blockIdx.x >> 7;  // 128 blocks per batch
  const int s_base = (blockIdx.x * 16) & (SS - 1);

  wct[(t & 15) * 68 + (t >> 4)] = w[t];
  if (t < DD) bs[t] = bias[t];

  // Combine: thread t -> (h = t>>4, row_l = t&15).
  {
    const int h = t >> 4, row_l = t & 15;
    const int bh = b * HH + h;
    float ax = 0.f, lx = 0.f;
#pragma unroll
    for (int jp = 0; jp < 8; ++jp) {
      const float2 p = P[(size_t)(jp * 64 + bh) * SS + s_base + row_l];
      ax += p.x; lx += p.y;
    }
    aol[row_l * 16 + h] = ax / lx;
  }
  __syncthreads();

  const int row_l = t >> 4, d = t & 15;
  const float4* ao4 = (const float4*)aol;
  const float4* wc4 = (const float4*)wct;

  float y = bs[d];
#pragma unroll
  for (int g = 0; g < 4; ++g) {
    const float4 xv = ao4[row_l * 4 + g];
    const float4 wv = wc4[d * 17 + g];
    y = fmaf(xv.x, wv.x, y);
    y = fmaf(xv.y, wv.y, y);
    y = fmaf(xv.z, wv.z, y);
    y = fmaf(xv.w, wv.w, y);
  }
  out[(size_t)blockIdx.x * 256 + t] = y;
}

// ---------------------------------------------------------------------------
extern "C" void kernel_launch(void* const* d_in, const int* in_sizes, int n_in,
                              void* d_out, int out_size, void* d_ws,
                              size_t ws_size, hipStream_t stream) {
  const float* x = (const float*)d_in[0];       // [B,S,D]
  const float* w_qkv = (const float*)d_in[1];   // [D, 3D]
  const float* b_qkv = (const float*)d_in[2];   // [3D]
  const float* w_out = (const float*)d_in[3];   // [D, D]
  const float* b_out = (const float*)d_in[4];   // [D]
  float* out = (float*)d_out;                   // [B,S,D] fp32

  float* ws = (float*)d_ws;
  float* Q = ws;             // [B][H][S]
  float* K = ws + BHS;       // [B][H][S]
  float* V = ws + 2 * BHS;   // [B][H][S]
  float2* P = (float2*)(ws + 3 * BHS);  // [8 jp][64 bh][2048 i] float2(a,l)

  qkv_kernel<<<512, 256, 0, stream>>>(x, w_qkv, b_qkv, Q, K, V);
  attn_kernel<<<1024, 256, 0, stream>>>(Q, K, V, P);
  proj_kernel<<<512, 256, 0, stream>>>(P, w_out, b_out, out);
}

// Round 7
// 95.563 us; speedup vs baseline: 2.1468x; 1.0030x over previous
//
#include <hip/hip_runtime.h>
#include <math.h>

// Problem constants (fixed by the reference).
#define BB 4
#define SS 2048
#define DD 16
#define HH 16

#if defined(__has_builtin)
#if __has_builtin(__builtin_amdgcn_exp2f)
#define EXP2(x) __builtin_amdgcn_exp2f(x)
#else
#define EXP2(x) exp2f(x)
#endif
#else
#define EXP2(x) exp2f(x)
#endif

#define LOG2E 1.44269504088896340736f

// ---------------------------------------------------------------------------
// Fused QKV + scalar-head causal attention.
// grid = 64 bh x 2 qp x 8 jp = 1024 blocks x 256 thr -> 4 blocks/CU.
//
// Stage 1: stage w_qkv (768 fl) + bias into LDS (coalesced).
// Stage 2: thread t = (m,u) computes k_j, v_j for j = (jp+8m)*64+u directly
//          from x (L2-resident) and LDS weight-column broadcasts -> Kl/Vl.
// Stage 3: wave w computes q for replicas qb_r = qp + 2*perm_r + 8r,
//          perm_r = (r&1) ? 3-w : w  (per-wave query-work balanced).
// Main loop (R6 logic, but ALL gating conditions are SGPRs via
// readfirstlane(w) -> s_cmp/s_cbranch instead of exec-mask dances):
//   slots m = 0..3 hold j-blocks jb = jp + 8m. Replica r: full iff m < fr_r,
//   fr_r = r + (d_r>0), d_r = qp+2*perm_r-jp; diagonal (lane-predicated) at
//   m == r iff d_r == 0. Partial (a,l) -> P[jp][bh][i].
// ---------------------------------------------------------------------------
#define ACC4(QS, LL, AA, K4, V4)                                   \
  {                                                                \
    float e;                                                       \
    e = EXP2((QS) * (K4).x); LL += e; AA = fmaf(e, (V4).x, AA);    \
    e = EXP2((QS) * (K4).y); LL += e; AA = fmaf(e, (V4).y, AA);    \
    e = EXP2((QS) * (K4).z); LL += e; AA = fmaf(e, (V4).z, AA);    \
    e = EXP2((QS) * (K4).w); LL += e; AA = fmaf(e, (V4).w, AA);    \
  }

#define ACC4P(QS, LL, AA, K4, V4, JJ)                              \
  {                                                                \
    float e;                                                       \
    e = EXP2((QS) * (K4).x); e = ((JJ) + 0 <= lane) ? e : 0.f;     \
    LL += e; AA = fmaf(e, (V4).x, AA);                             \
    e = EXP2((QS) * (K4).y); e = ((JJ) + 1 <= lane) ? e : 0.f;     \
    LL += e; AA = fmaf(e, (V4).y, AA);                             \
    e = EXP2((QS) * (K4).z); e = ((JJ) + 2 <= lane) ? e : 0.f;     \
    LL += e; AA = fmaf(e, (V4).z, AA);                             \
    e = EXP2((QS) * (K4).w); e = ((JJ) + 3 <= lane) ? e : 0.f;     \
    LL += e; AA = fmaf(e, (V4).w, AA);                             \
  }

__global__ __launch_bounds__(256, 4) void attn_fused_kernel(
    const float* __restrict__ x, const float* __restrict__ w_qkv,
    const float* __restrict__ b_qkv, float2* __restrict__ P) {
  __shared__ float ws[768];  // w_qkv[i][o] at ws[i*48+o]
  __shared__ float bs[48];
  __shared__ float Kl[256];  // 4 j-blocks (jb = jp + 8m) of 64 floats
  __shared__ float Vl[256];
  const int blk = blockIdx.x;
  const int jp = blk & 7;
  const int qp = (blk >> 3) & 1;
  const int bh = blk >> 4;  // 0..63
  const int b = bh >> 4, h = bh & 15;
  const int t = threadIdx.x;
  const int w = __builtin_amdgcn_readfirstlane(t >> 6);  // SGPR wave id
  const int lane = t & 63;

  // --- Stage 1: weights -> LDS (coalesced) ---
  ws[t] = w_qkv[t];
  ws[256 + t] = w_qkv[256 + t];
  ws[512 + t] = w_qkv[512 + t];
  if (t < 48) bs[t] = b_qkv[t];
  __syncthreads();

  // --- Stage 2: K,V for the 4 parity j-blocks (1 j per thread) ---
  {
    const int m = t >> 6;
    const int j = (jp + 8 * m) * 64 + lane;
    const float4* X4 = (const float4*)(x + ((size_t)b * SS + j) * DD);
    const float4 x0 = X4[0], x1 = X4[1], x2 = X4[2], x3 = X4[3];
    const float xr[16] = {x0.x, x0.y, x0.z, x0.w, x1.x, x1.y, x1.z, x1.w,
                          x2.x, x2.y, x2.z, x2.w, x3.x, x3.y, x3.z, x3.w};
    float k = bs[16 + h], v = bs[32 + h];
#pragma unroll
    for (int i = 0; i < 16; ++i) {  // ws reads are all-lane broadcasts: free
      k = fmaf(xr[i], ws[i * 48 + 16 + h], k);
      v = fmaf(xr[i], ws[i * 48 + 32 + h], v);
    }
    Kl[t] = k;  // t == m*64 + lane
    Vl[t] = v;
  }

  // --- Stage 3: q for this wave's 4 replicas ---
  int qbr[4];
  float qsv[4];
#pragma unroll
  for (int r = 0; r < 4; ++r) {
    const int perm = (r & 1) ? (3 - w) : w;
    qbr[r] = qp + 2 * perm + 8 * r;
    const int i = qbr[r] * 64 + lane;
    const float4* X4 = (const float4*)(x + ((size_t)b * SS + i) * DD);
    const float4 x0 = X4[0], x1 = X4[1], x2 = X4[2], x3 = X4[3];
    const float xr[16] = {x0.x, x0.y, x0.z, x0.w, x1.x, x1.y, x1.z, x1.w,
                          x2.x, x2.y, x2.z, x2.w, x3.x, x3.y, x3.z, x3.w};
    float q = bs[h];
#pragma unroll
    for (int ii = 0; ii < 16; ++ii) q = fmaf(xr[ii], ws[ii * 48 + h], q);
    qsv[r] = q * LOG2E;  // exp(q*k) = exp2(qs*k)
  }
  __syncthreads();

  // --- Main loop: all gating scalar (w, qp, jp are SGPRs) ---
  const int dA = qp + 2 * w - jp;        // replicas 0,2 (perm = w)
  const int dB = qp + 2 * (3 - w) - jp;  // replicas 1,3 (perm = 3-w)
  const int fr0 = 0 + ((dA > 0) ? 1 : 0);
  const int fr1 = 1 + ((dB > 0) ? 1 : 0);
  const int fr2 = 2 + ((dA > 0) ? 1 : 0);
  const int fr3 = 3 + ((dB > 0) ? 1 : 0);
  const bool diagA = (dA == 0), diagB = (dB == 0);
  const int MAXIDX = 3 + ((dB >= 0) ? 1 : 0);

  float l0 = 0.f, l1 = 0.f, l2 = 0.f, l3 = 0.f;
  float a0 = 0.f, a1 = 0.f, a2 = 0.f, a3 = 0.f;

  const float4* Kl4 = (const float4*)Kl;
  const float4* Vl4 = (const float4*)Vl;

  for (int m = 0; m < MAXIDX; ++m) {
    const bool f0 = m < fr0, f1 = m < fr1, f2 = m < fr2, f3 = m < fr3;
    const bool g0 = diagA && (m == 0), g1 = diagB && (m == 1),
               g2 = diagA && (m == 2), g3 = diagB && (m == 3);
#pragma unroll
    for (int s = 0; s < 4; ++s) {  // 16 j's per chunk, shared across replicas
      const float4 k0 = Kl4[m * 16 + s * 4 + 0];
      const float4 k1 = Kl4[m * 16 + s * 4 + 1];
      const float4 k2 = Kl4[m * 16 + s * 4 + 2];
      const float4 k3 = Kl4[m * 16 + s * 4 + 3];
      const float4 v0 = Vl4[m * 16 + s * 4 + 0];
      const float4 v1 = Vl4[m * 16 + s * 4 + 1];
      const float4 v2 = Vl4[m * 16 + s * 4 + 2];
      const float4 v3 = Vl4[m * 16 + s * 4 + 3];
      const int jj = s * 16;
      if (f0) {
        ACC4(qsv[0], l0, a0, k0, v0); ACC4(qsv[0], l0, a0, k1, v1);
        ACC4(qsv[0], l0, a0, k2, v2); ACC4(qsv[0], l0, a0, k3, v3);
      } else if (g0) {
        ACC4P(qsv[0], l0, a0, k0, v0, jj + 0); ACC4P(qsv[0], l0, a0, k1, v1, jj + 4);
        ACC4P(qsv[0], l0, a0, k2, v2, jj + 8); ACC4P(qsv[0], l0, a0, k3, v3, jj + 12);
      }
      if (f1) {
        ACC4(qsv[1], l1, a1, k0, v0); ACC4(qsv[1], l1, a1, k1, v1);
        ACC4(qsv[1], l1, a1, k2, v2); ACC4(qsv[1], l1, a1, k3, v3);
      } else if (g1) {
        ACC4P(qsv[1], l1, a1, k0, v0, jj + 0); ACC4P(qsv[1], l1, a1, k1, v1, jj + 4);
        ACC4P(qsv[1], l1, a1, k2, v2, jj + 8); ACC4P(qsv[1], l1, a1, k3, v3, jj + 12);
      }
      if (f2) {
        ACC4(qsv[2], l2, a2, k0, v0); ACC4(qsv[2], l2, a2, k1, v1);
        ACC4(qsv[2], l2, a2, k2, v2); ACC4(qsv[2], l2, a2, k3, v3);
      } else if (g2) {
        ACC4P(qsv[2], l2, a2, k0, v0, jj + 0); ACC4P(qsv[2], l2, a2, k1, v1, jj + 4);
        ACC4P(qsv[2], l2, a2, k2, v2, jj + 8); ACC4P(qsv[2], l2, a2, k3, v3, jj + 12);
      }
      if (f3) {
        ACC4(qsv[3], l3, a3, k0, v0); ACC4(qsv[3], l3, a3, k1, v1);
        ACC4(qsv[3], l3, a3, k2, v2); ACC4(qsv[3], l3, a3, k3, v3);
      } else if (g3) {
        ACC4P(qsv[3], l3, a3, k0, v0, jj + 0); ACC4P(qsv[3], l3, a3, k1, v1, jj + 4);
        ACC4P(qsv[3], l3, a3, k2, v2, jj + 8); ACC4P(qsv[3], l3, a3, k3, v3, jj + 12);
      }
    }
  }

  // Partial (a, l) per query-instance; coalesced float2 stores.
  float2* Pp = P + (size_t)(jp * 64 + bh) * SS;
  Pp[qbr[0] * 64 + lane] = make_float2(a0, l0);
  Pp[qbr[1] * 64 + lane] = make_float2(a1, l1);
  Pp[qbr[2] * 64 + lane] = make_float2(a2, l2);
  Pp[qbr[3] * 64 + lane] = make_float2(a3, l3);
}

// ---------------------------------------------------------------------------
// Kernel C: combine 8 partials -> AO[row][h] in LDS, then out = AO@w+b.
// 512 blocks x 256 threads; block = 16 rows.
// ---------------------------------------------------------------------------
__global__ __launch_bounds__(256) void proj_kernel(
    const float2* __restrict__ P, const float* __restrict__ w,
    const float* __restrict__ bias, float* __restrict__ out) {
  __shared__ float wct[DD * 68];  // column d at wct[d*68 + i]
  __shared__ float aol[256];      // aol[row_l*16 + h]
  __shared__ float bs[DD];
  const int t = threadIdx.x;
  const int b = blockIdx.x >> 7;  // 128 blocks per batch
  const int s_base = (blockIdx.x * 16) & (SS - 1);

  wct[(t & 15) * 68 + (t >> 4)] = w[t];
  if (t < DD) bs[t] = bias[t];

  // Combine: thread t -> (h = t>>4, row_l = t&15).
  {
    const int h = t >> 4, row_l = t & 15;
    const int bh = b * HH + h;
    float ax = 0.f, lx = 0.f;
#pragma unroll
    for (int jp = 0; jp < 8; ++jp) {
      const float2 p = P[(size_t)(jp * 64 + bh) * SS + s_base + row_l];
      ax += p.x; lx += p.y;
    }
    aol[row_l * 16 + h] = ax / lx;
  }
  __syncthreads();

  const int row_l = t >> 4, d = t & 15;
  const float4* ao4 = (const float4*)aol;
  const float4* wc4 = (const float4*)wct;

  float y = bs[d];
#pragma unroll
  for (int g = 0; g < 4; ++g) {
    const float4 xv = ao4[row_l * 4 + g];
    const float4 wv = wc4[d * 17 + g];
    y = fmaf(xv.x, wv.x, y);
    y = fmaf(xv.y, wv.y, y);
    y = fmaf(xv.z, wv.z, y);
    y = fmaf(xv.w, wv.w, y);
  }
  out[(size_t)blockIdx.x * 256 + t] = y;
}

// ---------------------------------------------------------------------------
extern "C" void kernel_launch(void* const* d_in, const int* in_sizes, int n_in,
                              void* d_out, int out_size, void* d_ws,
                              size_t ws_size, hipStream_t stream) {
  const float* x = (const float*)d_in[0];       // [B,S,D]
  const float* w_qkv = (const float*)d_in[1];   // [D, 3D]
  const float* b_qkv = (const float*)d_in[2];   // [3D]
  const float* w_out = (const float*)d_in[3];   // [D, D]
  const float* b_out = (const float*)d_in[4];   // [D]
  float* out = (float*)d_out;                   // [B,S,D] fp32

  float2* P = (float2*)d_ws;  // [8 jp][64 bh][2048 i] float2(a,l) = 8 MB

  attn_fused_kernel<<<1024, 256, 0, stream>>>(x, w_qkv, b_qkv, P);
  proj_kernel<<<512, 256, 0, stream>>>(P, w_out, b_out, out);
}

// Round 8
// 91.949 us; speedup vs baseline: 2.2312x; 1.0393x over previous
//
#include <hip/hip_runtime.h>
#include <math.h>

// Problem constants (fixed by the reference).
#define BB 4
#define SS 2048
#define DD 16
#define HH 16

#if defined(__has_builtin)
#if __has_builtin(__builtin_amdgcn_exp2f)
#define EXP2(x) __builtin_amdgcn_exp2f(x)
#else
#define EXP2(x) exp2f(x)
#endif
#else
#define EXP2(x) exp2f(x)
#endif

#define LOG2E 1.44269504088896340736f

// ---------------------------------------------------------------------------
// Slot processor: one 64-j slot (16 float4 groups) at LDS slot m.
// MASK bit r => replica r accumulates all 64 j's. DIAGR >= 0 => that replica
// runs the lane-predicated diagonal on this slot. All gating is compile-time;
// the body is one straight-line scheduling window; K/V loads shared.
// Two accumulator chains per replica (x,z -> chain0; y,w -> chain1).
// ---------------------------------------------------------------------------
template <int MASK, int DIAGR>
__device__ __forceinline__ void do_slot(const float4* __restrict__ Kl4,
                                        const float4* __restrict__ Vl4,
                                        int m, int lane,
                                        const float (&qs)[4],
                                        float (&l)[4][2], float (&a)[4][2]) {
#pragma unroll
  for (int g = 0; g < 16; ++g) {
    const float4 k4 = Kl4[m * 16 + g];
    const float4 v4 = Vl4[m * 16 + g];
    const int jj = 4 * g;
#pragma unroll
    for (int r = 0; r < 4; ++r) {
      if ((MASK >> r) & 1) {
        float e;
        e = EXP2(qs[r] * k4.x); l[r][0] += e; a[r][0] = fmaf(e, v4.x, a[r][0]);
        e = EXP2(qs[r] * k4.y); l[r][1] += e; a[r][1] = fmaf(e, v4.y, a[r][1]);
        e = EXP2(qs[r] * k4.z); l[r][0] += e; a[r][0] = fmaf(e, v4.z, a[r][0]);
        e = EXP2(qs[r] * k4.w); l[r][1] += e; a[r][1] = fmaf(e, v4.w, a[r][1]);
      } else if (r == DIAGR) {
        float e;
        e = EXP2(qs[r] * k4.x); e = (jj + 0 <= lane) ? e : 0.f;
        l[r][0] += e; a[r][0] = fmaf(e, v4.x, a[r][0]);
        e = EXP2(qs[r] * k4.y); e = (jj + 1 <= lane) ? e : 0.f;
        l[r][1] += e; a[r][1] = fmaf(e, v4.y, a[r][1]);
        e = EXP2(qs[r] * k4.z); e = (jj + 2 <= lane) ? e : 0.f;
        l[r][0] += e; a[r][0] = fmaf(e, v4.z, a[r][0]);
        e = EXP2(qs[r] * k4.w); e = (jj + 3 <= lane) ? e : 0.f;
        l[r][1] += e; a[r][1] = fmaf(e, v4.w, a[r][1]);
      }
    }
  }
}

// ---------------------------------------------------------------------------
// Fused QKV + scalar-head causal attention.
// grid = 64 bh x 2 qp x 8 jp = 1024 blocks x 256 thr -> 4 blocks/CU.
// Slots m = 0..3 hold j-blocks jb = jp + 8m. Replica r (wave w):
// qb_r = qp + 2*perm_r + 8r, perm_r = (r&1) ? 3-w : w. Full iff m < fr_r,
// fr_r = r + (d>0), d_r = qp + 2*perm_r - jp (dA for even r, dB for odd r);
// diagonal at m == r iff d == 0. Active-full sets per m are a fixed suffix
// plus at most one extra replica -> 2 scalar branches per slot, 8 total.
// ---------------------------------------------------------------------------
__global__ __launch_bounds__(256, 4) void attn_fused_kernel(
    const float* __restrict__ x, const float* __restrict__ w_qkv,
    const float* __restrict__ b_qkv, float2* __restrict__ P) {
  __shared__ float ws[768];  // w_qkv[i][o] at ws[i*48+o]
  __shared__ float bs[48];
  __shared__ float Kl[256];  // 4 j-blocks (jb = jp + 8m) of 64 floats
  __shared__ float Vl[256];
  const int blk = blockIdx.x;
  const int jp = blk & 7;
  const int qp = (blk >> 3) & 1;
  const int bh = blk >> 4;  // 0..63
  const int b = bh >> 4, h = bh & 15;
  const int t = threadIdx.x;
  const int w = __builtin_amdgcn_readfirstlane(t >> 6);  // SGPR wave id
  const int lane = t & 63;

  // --- Stage 1: weights -> LDS (coalesced) ---
  ws[t] = w_qkv[t];
  ws[256 + t] = w_qkv[256 + t];
  ws[512 + t] = w_qkv[512 + t];
  if (t < 48) bs[t] = b_qkv[t];
  __syncthreads();

  // --- Stage 2: K,V for the 4 parity j-blocks (1 j per thread) ---
  {
    const int m = t >> 6;
    const int j = (jp + 8 * m) * 64 + lane;
    const float4* X4 = (const float4*)(x + ((size_t)b * SS + j) * DD);
    const float4 x0 = X4[0], x1 = X4[1], x2 = X4[2], x3 = X4[3];
    const float xr[16] = {x0.x, x0.y, x0.z, x0.w, x1.x, x1.y, x1.z, x1.w,
                          x2.x, x2.y, x2.z, x2.w, x3.x, x3.y, x3.z, x3.w};
    float k = bs[16 + h], v = bs[32 + h];
#pragma unroll
    for (int i = 0; i < 16; ++i) {  // ws reads are all-lane broadcasts: free
      k = fmaf(xr[i], ws[i * 48 + 16 + h], k);
      v = fmaf(xr[i], ws[i * 48 + 32 + h], v);
    }
    Kl[t] = k;  // t == m*64 + lane
    Vl[t] = v;
  }

  // --- Stage 3: q for this wave's 4 replicas ---
  int qbr[4];
  float qs[4];
#pragma unroll
  for (int r = 0; r < 4; ++r) {
    const int perm = (r & 1) ? (3 - w) : w;
    qbr[r] = qp + 2 * perm + 8 * r;
    const int i = qbr[r] * 64 + lane;
    const float4* X4 = (const float4*)(x + ((size_t)b * SS + i) * DD);
    const float4 x0 = X4[0], x1 = X4[1], x2 = X4[2], x3 = X4[3];
    const float xr[16] = {x0.x, x0.y, x0.z, x0.w, x1.x, x1.y, x1.z, x1.w,
                          x2.x, x2.y, x2.z, x2.w, x3.x, x3.y, x3.z, x3.w};
    float q = bs[h];
#pragma unroll
    for (int ii = 0; ii < 16; ++ii) q = fmaf(xr[ii], ws[ii * 48 + h], q);
    qs[r] = q * LOG2E;  // exp(q*k) = exp2(qs*k)
  }
  __syncthreads();

  const int dA = qp + 2 * w - jp;        // replicas 0,2 (perm = w)
  const int dB = qp + 2 * (3 - w) - jp;  // replicas 1,3 (perm = 3-w)

  float l[4][2] = {{0.f, 0.f}, {0.f, 0.f}, {0.f, 0.f}, {0.f, 0.f}};
  float a[4][2] = {{0.f, 0.f}, {0.f, 0.f}, {0.f, 0.f}, {0.f, 0.f}};

  const float4* Kl4 = (const float4*)Kl;
  const float4* Vl4 = (const float4*)Vl;

  // Slot 0: base {1,2,3}; extra r0 full iff dA>0, diag iff dA==0.
  if (dA > 0)       do_slot<0b1111, -1>(Kl4, Vl4, 0, lane, qs, l, a);
  else if (dA == 0) do_slot<0b1110, 0>(Kl4, Vl4, 0, lane, qs, l, a);
  else              do_slot<0b1110, -1>(Kl4, Vl4, 0, lane, qs, l, a);
  // Slot 1: base {2,3}; extra r1.
  if (dB > 0)       do_slot<0b1110, -1>(Kl4, Vl4, 1, lane, qs, l, a);
  else if (dB == 0) do_slot<0b1100, 1>(Kl4, Vl4, 1, lane, qs, l, a);
  else              do_slot<0b1100, -1>(Kl4, Vl4, 1, lane, qs, l, a);
  // Slot 2: base {3}; extra r2.
  if (dA > 0)       do_slot<0b1100, -1>(Kl4, Vl4, 2, lane, qs, l, a);
  else if (dA == 0) do_slot<0b1000, 2>(Kl4, Vl4, 2, lane, qs, l, a);
  else              do_slot<0b1000, -1>(Kl4, Vl4, 2, lane, qs, l, a);
  // Slot 3: base {}; extra r3 (skip slot entirely if neither).
  if (dB > 0)       do_slot<0b1000, -1>(Kl4, Vl4, 3, lane, qs, l, a);
  else if (dB == 0) do_slot<0b0000, 3>(Kl4, Vl4, 3, lane, qs, l, a);

  // Partial (a, l) per query-instance; coalesced float2 stores.
  float2* Pp = P + (size_t)(jp * 64 + bh) * SS;
#pragma unroll
  for (int r = 0; r < 4; ++r) {
    Pp[qbr[r] * 64 + lane] = make_float2(a[r][0] + a[r][1], l[r][0] + l[r][1]);
  }
}

// ---------------------------------------------------------------------------
// Kernel C: combine 8 partials -> AO[row][h] in LDS, then out = AO@w+b.
// 512 blocks x 256 threads; block = 16 rows.
// ---------------------------------------------------------------------------
__global__ __launch_bounds__(256) void proj_kernel(
    const float2* __restrict__ P, const float* __restrict__ w,
    const float* __restrict__ bias, float* __restrict__ out) {
  __shared__ float wct[DD * 68];  // column d at wct[d*68 + i]
  __shared__ float aol[256];      // aol[row_l*16 + h]
  __shared__ float bs[DD];
  const int t = threadIdx.x;
  const int b = blockIdx.x >> 7;  // 128 blocks per batch
  const int s_base = (blockIdx.x * 16) & (SS - 1);

  wct[(t & 15) * 68 + (t >> 4)] = w[t];
  if (t < DD) bs[t] = bias[t];

  // Combine: thread t -> (h = t>>4, row_l = t&15).
  {
    const int h = t >> 4, row_l = t & 15;
    const int bh = b * HH + h;
    float ax = 0.f, lx = 0.f;
#pragma unroll
    for (int jp = 0; jp < 8; ++jp) {
      const float2 p = P[(size_t)(jp * 64 + bh) * SS + s_base + row_l];
      ax += p.x; lx += p.y;
    }
    aol[row_l * 16 + h] = ax / lx;
  }
  __syncthreads();

  const int row_l = t >> 4, d = t & 15;
  const float4* ao4 = (const float4*)aol;
  const float4* wc4 = (const float4*)wct;

  float y = bs[d];
#pragma unroll
  for (int g = 0; g < 4; ++g) {
    const float4 xv = ao4[row_l * 4 + g];
    const float4 wv = wc4[d * 17 + g];
    y = fmaf(xv.x, wv.x, y);
    y = fmaf(xv.y, wv.y, y);
    y = fmaf(xv.z, wv.z, y);
    y = fmaf(xv.w, wv.w, y);
  }
  out[(size_t)blockIdx.x * 256 + t] = y;
}

// ---------------------------------------------------------------------------
extern "C" void kernel_launch(void* const* d_in, const int* in_sizes, int n_in,
                              void* d_out, int out_size, void* d_ws,
                              size_t ws_size, hipStream_t stream) {
  const float* x = (const float*)d_in[0];       // [B,S,D]
  const float* w_qkv = (const float*)d_in[1];   // [D, 3D]
  const float* b_qkv = (const float*)d_in[2];   // [3D]
  const float* w_out = (const float*)d_in[3];   // [D, D]
  const float* b_out = (const float*)d_in[4];   // [D]
  float* out = (float*)d_out;                   // [B,S,D] fp32

  float2* P = (float2*)d_ws;  // [8 jp][64 bh][2048 i] float2(a,l) = 8 MB

  attn_fused_kernel<<<1024, 256, 0, stream>>>(x, w_qkv, b_qkv, P);
  proj_kernel<<<512, 256, 0, stream>>>(P, w_out, b_out, out);
}